// Round 9
// baseline (191.651 us; speedup 1.0000x reference)
//
#include <hip/hip_runtime.h>

// Problem constants: N=2, L=2048, E=1024, H=16, D=64
// I/O dtypes: float tensors fp32, masks int32, output fp32.
// ws (bf16): qp (n,h,l,d) | kc (n,h,c,d) compacted rows | vcT (n,h,d,c)
// compacted cols | ao (n,l,h*64+d) | Wob | excl int[2][2049] (prefix of mask).

typedef __bf16 bf16_t;
typedef __bf16 bf16x4 __attribute__((ext_vector_type(4)));
typedef __bf16 bf16x8 __attribute__((ext_vector_type(8)));
typedef float f32x4 __attribute__((ext_vector_type(4)));

#define MFMA16(a, b, c) __builtin_amdgcn_mfma_f32_16x16x32_bf16((a), (b), (c), 0, 0, 0)

#define GLOAD_LDS16(gp, lp)                                              \
    __builtin_amdgcn_global_load_lds(                                    \
        (const __attribute__((address_space(1))) void*)(gp),             \
        (__attribute__((address_space(3))) void*)(lp), 16, 0, 0)

__device__ inline bf16x8 cvt8(const float* __restrict__ p, float scale) {
    f32x4 a = *(const f32x4*)p;
    f32x4 b = *(const f32x4*)(p + 4);
    bf16x8 r;
    r[0] = (bf16_t)(a[0] * scale); r[1] = (bf16_t)(a[1] * scale);
    r[2] = (bf16_t)(a[2] * scale); r[3] = (bf16_t)(a[3] * scale);
    r[4] = (bf16_t)(b[0] * scale); r[5] = (bf16_t)(b[1] * scale);
    r[6] = (bf16_t)(b[2] * scale); r[7] = (bf16_t)(b[3] * scale);
    return r;
}

// ---------------------------------------------------------------------------
// Kernel 0: PARALLEL exclusive prefix scan of mask validity. Grid = 2 (n).
// Wave-inclusive scan via shfl_up; cross-wave via 4-entry LDS. No serial loop.
// ---------------------------------------------------------------------------
__global__ __launch_bounds__(256) void scan_kernel(const int* __restrict__ msk,
                                                   int* __restrict__ excl)
{
    __shared__ int wsum[4];
    const int t = threadIdx.x, lane = t & 63, w = t >> 6;
    const int n = blockIdx.x;
    const int* m = msk + n * 2048;
    int* e = excl + n * 2049;

    int v[8], s = 0;
    #pragma unroll
    for (int j = 0; j < 8; j++) { v[j] = (m[t * 8 + j] != 0); s += v[j]; }

    // inclusive scan of s across the wave
    int isc = s;
    #pragma unroll
    for (int d = 1; d < 64; d <<= 1) {
        int x = __shfl_up(isc, d);
        if (lane >= d) isc += x;
    }
    if (lane == 63) wsum[w] = isc;
    __syncthreads();

    int woff = 0;
    #pragma unroll
    for (int i = 0; i < 4; i++) if (i < w) woff += wsum[i];
    if (t == 0) e[2048] = wsum[0] + wsum[1] + wsum[2] + wsum[3];

    int a = woff + isc - s;          // exclusive prefix for this thread's chunk
    #pragma unroll
    for (int j = 0; j < 8; j++) { e[t * 8 + j] = a; a += v[j]; }
}

// ---------------------------------------------------------------------------
// Kernel 1: fused projections + Wo pre-convert (unchanged from round 8).
// ---------------------------------------------------------------------------
__global__ __launch_bounds__(256) void qkv_proj_kernel(
    const float* __restrict__ qin, const float* __restrict__ kin,
    const float* __restrict__ vin,
    const float* __restrict__ Wq, const float* __restrict__ Wk,
    const float* __restrict__ Wv, const float* __restrict__ Wo,
    const int* __restrict__ excl,
    bf16_t* __restrict__ qp, bf16_t* __restrict__ kc, bf16_t* __restrict__ vcT,
    bf16_t* __restrict__ Wob)
{
    __shared__ __align__(16) char smem[51200];

    const int t = threadIdx.x;
    const int w = t >> 6, lane = t & 63, quad = lane >> 4, l16 = lane & 15;

    if (blockIdx.y == 3) {               // Wo cvt
        int idx = blockIdx.x * 1024 + t * 4;
        f32x4 v = *(const f32x4*)&Wo[idx];
        bf16x4 r;
        r[0] = (bf16_t)v[0]; r[1] = (bf16_t)v[1];
        r[2] = (bf16_t)v[2]; r[3] = (bf16_t)v[3];
        *(bf16x4*)&Wob[idx] = r;
        return;
    }

    if (blockIdx.y == 2) {               // V -> vcT (n,h,d,c) compacted
        bf16_t* Ct = (bf16_t*)smem;                   // [64][72]
        short* mapS = (short*)(smem + 16384);         // [64]
        const int h = blockIdx.x & 15;
        const int tb = (blockIdx.x >> 4) * 64;
        const int n = tb >> 11, l0 = tb & 2047;
        const int tg = tb + w * 16 + l16;

        bf16x8 b0 = cvt8(&vin[(size_t)tg * 1024 + h * 64 + quad * 8], 1.0f);
        bf16x8 b1 = cvt8(&vin[(size_t)tg * 1024 + h * 64 + 32 + quad * 8], 1.0f);

        const int cbase = excl[n * 2049 + l0];
        const int cnt   = excl[n * 2049 + l0 + 64] - cbase;
        if (t < 64) {
            int c  = excl[n * 2049 + l0 + t];
            int c1 = excl[n * 2049 + l0 + t + 1];
            if (c1 > c) mapS[c - cbase] = (short)t;
        }

        #pragma unroll
        for (int nt = 0; nt < 4; nt++) {
            bf16x8 a0 = cvt8(&Wv[(nt * 16 + l16) * 64 + quad * 8], 1.0f);
            bf16x8 a1 = cvt8(&Wv[(nt * 16 + l16) * 64 + 32 + quad * 8], 1.0f);
            f32x4 acc = {0.f, 0.f, 0.f, 0.f};
            acc = MFMA16(a0, b0, acc);
            acc = MFMA16(a1, b1, acc);
            #pragma unroll
            for (int r = 0; r < 4; r++)
                Ct[(nt * 16 + quad * 4 + r) * 72 + w * 16 + l16] = (bf16_t)acc[r];
        }
        __syncthreads();
        const int p = t & 63, rg = t >> 6;
        if (p < cnt) {
            int j = mapS[p];
            size_t ob = ((size_t)(n * 16 + h)) * 131072 + cbase + p;
            #pragma unroll
            for (int rr = 0; rr < 16; rr++) {
                int r = rg * 16 + rr;
                vcT[ob + (size_t)r * 2048] = Ct[r * 72 + j];
            }
        }
        return;
    }

    // ---- y=0/1: Q (dense) or K (compacted rows), 128 rows/block ----
    if (blockIdx.x >= 512) return;
    const bool isK = (blockIdx.y == 1);
    const float* x; const float* W; float scale;
    if (!isK) { x = qin; W = Wq; scale = 0.03125f; }
    else      { x = kin; W = Wk; scale = 1.0f; }

    float* Xs = (float*)smem;                         // [128][64]
    bf16_t* Ct2 = (bf16_t*)(smem + 32768);            // [128][72]

    const int g0 = blockIdx.x * 128;

    #pragma unroll
    for (int j = 0; j < 8; j++) {
        int br = w * 32 + j * 4;
        GLOAD_LDS16(&x[(size_t)(g0 + br) * 64 + lane * 4], &Xs[br * 64]);
    }
    __syncthreads();

    const int rbase = w * 32;
    bf16x8 a[2][2];
    #pragma unroll
    for (int qs = 0; qs < 2; qs++)
        #pragma unroll
        for (int c = 0; c < 2; c++)
            a[qs][c] = cvt8(&Xs[(rbase + qs * 16 + l16) * 64 + c * 32 + quad * 8], scale);

    f32x4 acc[4][2];
    #pragma unroll
    for (int nt = 0; nt < 4; nt++) {
        bf16x8 b0 = cvt8(&W[(nt * 16 + l16) * 64 + quad * 8], 1.0f);
        bf16x8 b1 = cvt8(&W[(nt * 16 + l16) * 64 + 32 + quad * 8], 1.0f);
        #pragma unroll
        for (int qs = 0; qs < 2; qs++) {
            f32x4 z = {0.f, 0.f, 0.f, 0.f};
            z = MFMA16(a[qs][0], b0, z);
            z = MFMA16(a[qs][1], b1, z);
            acc[nt][qs] = z;
        }
    }

    #pragma unroll
    for (int nt = 0; nt < 4; nt++)
        #pragma unroll
        for (int qs = 0; qs < 2; qs++)
            #pragma unroll
            for (int r = 0; r < 4; r++)
                Ct2[(rbase + qs * 16 + quad * 4 + r) * 72 + nt * 16 + l16] = (bf16_t)acc[nt][qs][r];
    __syncthreads();

    #pragma unroll
    for (int it = 0; it < 4; it++) {
        int j = it * 32 + (t >> 3);
        int g = g0 + j, h2 = g & 15, token = g >> 4;
        int n2 = token >> 11, l = token & 2047;
        bf16x8 val = *(const bf16x8*)&Ct2[j * 72 + (t & 7) * 8];
        if (isK) {
            int c  = excl[n2 * 2049 + l];
            int c1 = excl[n2 * 2049 + l + 1];
            if (c1 > c)
                *(bf16x8*)&kc[(((size_t)(n2 * 16 + h2)) * 2048 + c) * 64 + (t & 7) * 8] = val;
        } else {
            *(bf16x8*)&qp[(((size_t)(n2 * 16 + h2)) * 2048 + l) * 64 + (t & 7) * 8] = val;
        }
    }
}

// ---------------------------------------------------------------------------
// Kernel 2: flash attention on compacted K/V. NOW 8 waves x 16 q = 128 q rows
// per block (512 threads): per-wave serial chain halved, 16 waves/CU resident
// (was 8) to hide the MFMA->exp->LDS->MFMA dependency. LDS unchanged 51.2 KB.
// ---------------------------------------------------------------------------
__global__ __launch_bounds__(512) void attn_kernel(
    const bf16_t* __restrict__ qp, const bf16_t* __restrict__ kc,
    const bf16_t* __restrict__ vcT, const int* __restrict__ excl,
    bf16_t* __restrict__ ao)
{
    __shared__ bf16_t Kt[2][64][64];   // (kk, d) unpadded (global_load_lds dst)
    __shared__ bf16_t Vt[2][64][64];   // (d, kk) unpadded
    __shared__ bf16_t PwT[8][16][72];  // per-wave P^T as [q][kk], padded

    const int t = threadIdx.x;
    const int w = t >> 6, lane = t & 63, quad = lane >> 4, l16 = lane & 15;

    // XCD-grouping swizzle: blocks of one nh share (id mod 8)
    const int flat = blockIdx.x;
    const int xcd = flat & 7, slot = flat >> 3;
    const int nh = xcd * 4 + (slot >> 4), qb = slot & 15;
    const int n = nh >> 4, h = nh & 15;
    const int qbase = qb * 128 + w * 16;         // wave's 16 q rows
    const size_t nhbase = (size_t)nh * 131072;

    const int Lc = excl[n * 2049 + 2048];
    const int ntiles = (Lc + 63) >> 6;

    // Q B-frags: B[k=d][n=q=l16], 2 k-chunks
    bf16x8 aq[2];
    #pragma unroll
    for (int c = 0; c < 2; c++)
        aq[c] = *(const bf16x8*)&qp[nhbase + (size_t)(qbase + l16) * 64 + c * 32 + quad * 8];

    f32x4 o[4];                         // o[dt]: O^T[d=dt*16+quad*4+r][q=l16]
    float lsum = 0.f;
    #pragma unroll
    for (int dt = 0; dt < 4; dt++) { o[dt][0] = 0.f; o[dt][1] = 0.f; o[dt][2] = 0.f; o[dt][3] = 0.f; }

    const int srow = w * 8;              // wave's 8 staging rows (8 waves x 8 = 64)

    // ---- prologue: stage tile 0 into buffer 0 (1 K + 1 V instr per wave) ----
    GLOAD_LDS16(&kc[nhbase + (size_t)srow * 64 + lane * 8], &Kt[0][srow][0]);
    GLOAD_LDS16(&vcT[nhbase + (size_t)(srow + (lane >> 3)) * 2048 + (lane & 7) * 8],
                &Vt[0][srow][0]);

    for (int i = 0; i < ntiles; i++) {
        const int cb = i & 1, nb = cb ^ 1;
        const int k0 = i * 64;
        __syncthreads();   // own loads drained (buf cb ready); all waves done with buf nb

        if (i + 1 < ntiles) {
            const int kn = k0 + 64;
            GLOAD_LDS16(&kc[nhbase + (size_t)(kn + srow) * 64 + lane * 8], &Kt[nb][srow][0]);
            GLOAD_LDS16(&vcT[nhbase + (size_t)(srow + (lane >> 3)) * 2048 + kn + (lane & 7) * 8],
                        &Vt[nb][srow][0]);
        }

        // ---- S^T = K Q^T: 4 kk-tiles ----
        f32x4 st[4];
        #pragma unroll
        for (int ct = 0; ct < 4; ct++) {
            bf16x8 kb0 = *(const bf16x8*)&Kt[cb][ct * 16 + l16][quad * 8];
            bf16x8 kb1 = *(const bf16x8*)&Kt[cb][ct * 16 + l16][32 + quad * 8];
            f32x4 acc = {0.f, 0.f, 0.f, 0.f};
            acc = MFMA16(kb0, aq[0], acc);
            acc = MFMA16(kb1, aq[1], acc);
            st[ct] = acc;
        }

        // ---- exp + l accumulate + P^T store (b64, contiguous kk) ----
        if (k0 + 64 <= Lc) {
            #pragma unroll
            for (int ct = 0; ct < 4; ct++) {
                bf16x4 pk;
                #pragma unroll
                for (int r = 0; r < 4; r++) {
                    float p = __expf(st[ct][r]);
                    lsum += p;
                    pk[r] = (bf16_t)p;
                }
                *(bf16x4*)&PwT[w][l16][ct * 16 + quad * 4] = pk;
            }
        } else {
            #pragma unroll
            for (int ct = 0; ct < 4; ct++) {
                bf16x4 pk;
                #pragma unroll
                for (int r = 0; r < 4; r++) {
                    int kk = k0 + ct * 16 + quad * 4 + r;
                    float p = (kk < Lc) ? __expf(st[ct][r]) : 0.0f;
                    lsum += p;
                    pk[r] = (bf16_t)p;
                }
                *(bf16x4*)&PwT[w][l16][ct * 16 + quad * 4] = pk;
            }
        }
        // wave-local LDS write->read drain (lockstep: all lanes in wave)
        asm volatile("s_waitcnt lgkmcnt(0)" ::: "memory");

        // ---- P^T B-frags + PV: O^T = V^T P^T ----
        bf16x8 bp0 = *(const bf16x8*)&PwT[w][l16][quad * 8];
        bf16x8 bp1 = *(const bf16x8*)&PwT[w][l16][32 + quad * 8];
        #pragma unroll
        for (int dt = 0; dt < 4; dt++) {
            bf16x8 va0 = *(const bf16x8*)&Vt[cb][dt * 16 + l16][quad * 8];
            bf16x8 va1 = *(const bf16x8*)&Vt[cb][dt * 16 + l16][32 + quad * 8];
            o[dt] = MFMA16(va0, bp0, o[dt]);
            o[dt] = MFMA16(va1, bp1, o[dt]);
        }
    }

    // ---- epilogue: l across quads via 2 shuffles; O^T scaled store ----
    {
        float v = lsum;
        v += __shfl_xor(v, 16);
        v += __shfl_xor(v, 32);
        float inv = 1.0f / v;
        const int q = qbase + l16;
        const size_t base = ((size_t)n * 2048 + q) * 1024 + h * 64;
        #pragma unroll
        for (int dt = 0; dt < 4; dt++) {
            bf16x4 ov;
            #pragma unroll
            for (int r = 0; r < 4; r++) ov[r] = (bf16_t)(o[dt][r] * inv);
            *(bf16x4*)&ao[base + dt * 16 + quad * 4] = ov;
        }
    }
}

// ---------------------------------------------------------------------------
// Kernel 3: out = X @ Wob^T + bo.  Double-buffered LDS GEMM (unchanged).
// ---------------------------------------------------------------------------
__global__ __launch_bounds__(256, 2) void out_proj_kernel(
    const bf16_t* __restrict__ X, const bf16_t* __restrict__ Wob,
    const float* __restrict__ bo, float* __restrict__ out)
{
    __shared__ bf16_t Xs[2][128][64];
    __shared__ bf16_t Ws[2][64][64];

    const int t = threadIdx.x;
    const int w = t >> 6, lane = t & 63, quad = lane >> 4, l16 = lane & 15;
    const int Mbase = blockIdx.x * 128;
    const int Nbase = blockIdx.y * 64;
    const int mrow = (w & 1) * 64;
    const int ncol = (w >> 1) * 32;

    f32x4 acc[4][2];
    #pragma unroll
    for (int mi = 0; mi < 4; mi++)
        #pragma unroll
        for (int ni = 0; ni < 2; ni++) {
            acc[mi][ni][0] = 0.f; acc[mi][ni][1] = 0.f;
            acc[mi][ni][2] = 0.f; acc[mi][ni][3] = 0.f;
        }

    #pragma unroll
    for (int j = 0; j < 4; j++) {
        int br = w * 32 + j * 8;
        GLOAD_LDS16(&X[(size_t)(Mbase + br + (lane >> 3)) * 1024 + (lane & 7) * 8],
                    &Xs[0][br][0]);
    }
    #pragma unroll
    for (int j = 0; j < 2; j++) {
        int br = w * 16 + j * 8;
        GLOAD_LDS16(&Wob[(size_t)(Nbase + br + (lane >> 3)) * 1024 + (lane & 7) * 8],
                    &Ws[0][br][0]);
    }

    for (int i = 0; i < 16; i++) {
        const int cb = i & 1, nb = cb ^ 1;
        __syncthreads();

        if (i < 15) {
            const int kn = (i + 1) * 64;
            #pragma unroll
            for (int j = 0; j < 4; j++) {
                int br = w * 32 + j * 8;
                GLOAD_LDS16(&X[(size_t)(Mbase + br + (lane >> 3)) * 1024 + kn + (lane & 7) * 8],
                            &Xs[nb][br][0]);
            }
            #pragma unroll
            for (int j = 0; j < 2; j++) {
                int br = w * 16 + j * 8;
                GLOAD_LDS16(&Wob[(size_t)(Nbase + br + (lane >> 3)) * 1024 + kn + (lane & 7) * 8],
                            &Ws[nb][br][0]);
            }
        }

        #pragma unroll
        for (int c = 0; c < 2; c++) {
            bf16x8 bfr[2];
            #pragma unroll
            for (int ni = 0; ni < 2; ni++)
                bfr[ni] = *(const bf16x8*)&Ws[cb][ncol + ni * 16 + l16][c * 32 + quad * 8];
            #pragma unroll
            for (int mi = 0; mi < 4; mi++) {
                bf16x8 afr = *(const bf16x8*)&Xs[cb][mrow + mi * 16 + l16][c * 32 + quad * 8];
                #pragma unroll
                for (int ni = 0; ni < 2; ni++)
                    acc[mi][ni] = MFMA16(afr, bfr[ni], acc[mi][ni]);
            }
        }
    }

    #pragma unroll
    for (int ni = 0; ni < 2; ni++) {
        float b = bo[Nbase + ncol + ni * 16 + l16];
        #pragma unroll
        for (int mi = 0; mi < 4; mi++) {
            #pragma unroll
            for (int r = 0; r < 4; r++) {
                int row = Mbase + mrow + mi * 16 + quad * 4 + r;
                out[(size_t)row * 1024 + Nbase + ncol + ni * 16 + l16] = acc[mi][ni][r] + b;
            }
        }
    }
}

// ---------------------------------------------------------------------------
extern "C" void kernel_launch(void* const* d_in, const int* in_sizes, int n_in,
                              void* d_out, int out_size, void* d_ws, size_t ws_size,
                              hipStream_t stream)
{
    const float* qin = (const float*)d_in[0];
    const float* kin = (const float*)d_in[1];
    const float* vin = (const float*)d_in[2];
    const int*   msk = (const int*)d_in[3];
    const float* Wq  = (const float*)d_in[4];
    const float* Wk  = (const float*)d_in[5];
    const float* Wv  = (const float*)d_in[6];
    const float* Wo  = (const float*)d_in[7];
    const float* bo  = (const float*)d_in[8];
    float* out = (float*)d_out;

    bf16_t* ws  = (bf16_t*)d_ws;
    bf16_t* qp  = ws;                  // (n,h,l,d)  4M elts
    bf16_t* kc  = ws + 4194304;        // (n,h,c,d)  4M (first Lc rows valid)
    bf16_t* vcT = ws + 8388608;        // (n,h,d,c)  4M (first Lc cols valid)
    bf16_t* ao  = ws + 12582912;       // (n,l,h*64+d) 4M
    bf16_t* Wob = ws + 16777216;       // bf16 Wo   1M
    int* excl   = (int*)(ws + 17825792);  // 2 x 2049 ints

    scan_kernel<<<dim3(2), 256, 0, stream>>>(msk, excl);
    qkv_proj_kernel<<<dim3(1024, 4), 256, 0, stream>>>(qin, kin, vin, Wq, Wk, Wv, Wo,
                                                        excl, qp, kc, vcT, Wob);
    attn_kernel<<<dim3(512), 512, 0, stream>>>(qp, kc, vcT, excl, ao);
    out_proj_kernel<<<dim3(32, 16), 256, 0, stream>>>(ao, Wob, bo, out);
}